// Round 7
// baseline (691.006 us; speedup 1.0000x reference)
//
#include <hip/hip_runtime.h>
#include <stdint.h>

// ---------------------------------------------------------------------------
// TransformerBlock on MI355X (gfx950)
//   x1  = x + ((softmax_causal((ln1(x)@qk)@ln1(x)^T / 32))@ln1(x))@ov
//   out = x1 + lrelu(lrelu(lrelu(ln2(x1)@W_up^T+b_up)@W_h^T+b_h)@W_down^T+b_down)
// Big MLP GEMMs: 256x256-tile 8-wave, m201-style register-pipelined
// sub-phases (reads for phase P+1 issued in phase P; 2 barriers/sub-phase;
// vmcnt(6) once per K-tile).  XCD-swizzled grids (T1/m204) everywhere.
// Everything else: m97-style 128x128 2-phase GEMM. x1 lives in d_out.
// ---------------------------------------------------------------------------

typedef __attribute__((ext_vector_type(4))) float  f32x4;
typedef __attribute__((ext_vector_type(8))) __bf16 bf16v8;
typedef __attribute__((ext_vector_type(8))) unsigned short u16x8;
typedef unsigned short ushort_t;   // bf16 bit storage
typedef unsigned int   u32;

#define SLOPE 0.01f

__device__ __forceinline__ ushort_t f2bf(float f) {
  u32 u = __builtin_bit_cast(u32, f);
  u32 r = (u + 0x7FFFu + ((u >> 16) & 1u)) >> 16;
  return (ushort_t)r;
}
__device__ __forceinline__ float bf2f(ushort_t b) {
  u32 u = ((u32)b) << 16;
  return __builtin_bit_cast(float, u);
}

__device__ __forceinline__ void gload_lds16(const void* g, void* l) {
  __builtin_amdgcn_global_load_lds(
      (const __attribute__((address_space(1))) u32*)g,
      (__attribute__((address_space(3))) u32*)l, 16, 0, 0);
}

// ===========================================================================
// 256x256 8-wave NT GEMM, register-pipelined sub-phases (m201 shape).
// BK=32; LDS = 4 rotating bufs x {A,B} x [256][32] bf16 = 4x32KB = 128KB.
// Swizzle (T2, rule-21): 16B slot ^= (row>>1)&3; linear LDS dest,
// inverse-swizzled GLOBAL source, swizzled ds_read.  Conflicts: 0 (R4-R6).
// Tile t = 2 sub-phases:
//  h0: {read avHI(t) (4 ds) | STAGE_A(t+3) (2 gload) | barrier |
//       16 MFMA mf0-3 (avLO(t),bv(t): read during (t-1,h1)) |
//       vmcnt(6) | barrier}
//  h1: {read avLO(t+1)+bv(t+1) (8 ds) | STAGE_B(t+3) (2 gload) | barrier |
//       16 MFMA mf4-7 (avHI(t): read in h0) | barrier}
// Hazard proof:
//  * vmcnt(6)@h0-end: pending <= {t+1:4(from t-2), t+2:4(from t-1),
//    t+3A:2(this phase)} = 10 -> retires tile t+1's 4 loads before (t,h1)
//    reads its LDS.  Tail: vmcnt(4) when t+3>=nt, vmcnt(0) when t+2>=nt.
//  * STAGE(t+3) overwrites buf[(t-1)&3]; last reads of tile t-1 (avHI in
//    (t-1,h0)) are consumed by (t-1,h1)'s MFMA (lgkm dep) before that
//    phase's end barrier; STAGE issues after it.
//  * Every MFMA cluster's inputs were ds_read one sub-phase earlier ->
//    no lgkm stall inside clusters.
// Register rotation via unroll-2 (all indices static).  nt must be EVEN.
// M,N mult of 256, K mult of 64.  EPI2: bias+leakyrelu -> bf16.
// ===========================================================================
template<int EPI>
__global__ __launch_bounds__(512, 1)
void gemm_nt8(const ushort_t* __restrict__ A, const ushort_t* __restrict__ B,
              void* __restrict__ Cv, const float* __restrict__ bias,
              int M, int N, int K)
{
  extern __shared__ char smem[];
  const ushort_t* lds = (const ushort_t*)smem;
  const int tid = threadIdx.x;
  const int l   = tid & 63;
  // T1: bijective XCD swizzle (m204)
  const int nwg = gridDim.x * gridDim.y;
  const int orig = blockIdx.y * gridDim.x + blockIdx.x;
  const int q8 = nwg >> 3, r8 = nwg & 7;
  const int xcd = orig & 7, io = orig >> 3;
  const int logical = (xcd < r8 ? xcd * (q8 + 1) : r8 * (q8 + 1) + (xcd - r8) * q8) + io;
  const int m0 = (logical / gridDim.x) * 256;
  const int n0 = (logical % gridDim.x) * 256;
  const int wid = tid >> 6;
  const int wm = (wid >> 2) * 128;   // 2 wave-rows
  const int wn = (wid & 3) * 64;     // 4 wave-cols
  const int nt = K >> 5;             // K-tiles of 32 (even)

  // staging: thread fills LDS bytes [tid*16, tid*16+16): row=tid>>2,
  // 16B slot = tid&3; global source slot pre-swizzled: slot ^ ((row>>1)&3)
  const int  sg      = (((tid & 3) ^ ((tid >> 3) & 3))) * 8;  // elems
  const long rowA0   = (long)(m0 +       (tid >> 2)) * K;
  const long rowA1   = (long)(m0 + 128 + (tid >> 2)) * K;
  const long rowB0   = (long)(n0 +       (tid >> 2)) * K;
  const long rowB1   = (long)(n0 + 128 + (tid >> 2)) * K;
  const int  wbase16 = (tid & ~63) * 16;                      // bytes

#define STAGE_A(TT) do {                                                      \
    const long _k  = (long)(TT) * 32;                                         \
    char* _ra = (char*)smem + ((TT) & 3) * 32768 + wbase16;                   \
    gload_lds16(A + rowA0 + _k + sg, _ra);                                    \
    gload_lds16(A + rowA1 + _k + sg, _ra + 8192);                             \
  } while (0)
#define STAGE_B(TT) do {                                                      \
    const long _k  = (long)(TT) * 32;                                         \
    char* _rb = (char*)smem + ((TT) & 3) * 32768 + 16384 + wbase16;           \
    gload_lds16(B + rowB0 + _k + sg, _rb);                                    \
    gload_lds16(B + rowB1 + _k + sg, _rb + 8192);                             \
  } while (0)

  // fragment-read constants
  const int fr  = l & 15;
  const int fsl = (((l >> 4) ^ ((l >> 1) & 3))) * 8;  // swizzled 16B slot, elems

  f32x4 acc[8][4] = {};
  bf16v8 avL0[4], bv0[4], avL1[4], bv1[4], avH[4];

  // prologue: stage tiles 0..2; tile0 ready; read tile0 low-frags
  STAGE_A(0); STAGE_B(0);
  STAGE_A(1); STAGE_B(1);
  STAGE_A(2); STAGE_B(2);
  asm volatile("s_waitcnt vmcnt(8)" ::: "memory");
  __builtin_amdgcn_s_barrier();
  __builtin_amdgcn_sched_barrier(0);
  {
    const ushort_t* rA = lds +        (wm + fr) * 32 + fsl;
    const ushort_t* rB = lds + 8192 + (wn + fr) * 32 + fsl;
#pragma unroll
    for (int j = 0; j < 4; j++) bv0[j]  = *(const bf16v8*)(rB + j * 512);
#pragma unroll
    for (int j = 0; j < 4; j++) avL0[j] = *(const bf16v8*)(rA + j * 512);
  }

#define TILE(T, avL, bvv, avLn, bvn) do {                                     \
    const int _buf = (T) & 3;                                                 \
    const ushort_t* _rA = lds + _buf * 16384 +        (wm + fr) * 32 + fsl;   \
    /* ---- sub-phase h0 ---- */                                              \
    _Pragma("unroll")                                                         \
    for (int j = 0; j < 4; j++) avH[j] = *(const bf16v8*)(_rA + (j + 4) * 512);\
    if ((T) + 3 < nt) STAGE_A((T) + 3);                                       \
    __builtin_amdgcn_s_barrier();                                             \
    __builtin_amdgcn_s_setprio(1);                                            \
    _Pragma("unroll")                                                         \
    for (int mf = 0; mf < 4; mf++)                                            \
      _Pragma("unroll")                                                       \
      for (int nf = 0; nf < 4; nf++)                                          \
        acc[mf][nf] = __builtin_amdgcn_mfma_f32_16x16x32_bf16(                \
            avL[mf], bvv[nf], acc[mf][nf], 0, 0, 0);                          \
    __builtin_amdgcn_s_setprio(0);                                            \
    if ((T) + 3 < nt)      { asm volatile("s_waitcnt vmcnt(6)" ::: "memory"); }\
    else if ((T) + 2 < nt) { asm volatile("s_waitcnt vmcnt(4)" ::: "memory"); }\
    else                   { asm volatile("s_waitcnt vmcnt(0)" ::: "memory"); }\
    __builtin_amdgcn_s_barrier();                                             \
    __builtin_amdgcn_sched_barrier(0);                                        \
    /* ---- sub-phase h1 ---- */                                              \
    if ((T) + 1 < nt) {                                                       \
      const int _bufn = ((T) + 1) & 3;                                        \
      const ushort_t* _rAn = lds + _bufn * 16384 +        (wm + fr) * 32 + fsl;\
      const ushort_t* _rBn = lds + _bufn * 16384 + 8192 + (wn + fr) * 32 + fsl;\
      _Pragma("unroll")                                                       \
      for (int j = 0; j < 4; j++) bvn[j]  = *(const bf16v8*)(_rBn + j * 512); \
      _Pragma("unroll")                                                       \
      for (int j = 0; j < 4; j++) avLn[j] = *(const bf16v8*)(_rAn + j * 512); \
    }                                                                         \
    if ((T) + 3 < nt) STAGE_B((T) + 3);                                       \
    __builtin_amdgcn_s_barrier();                                             \
    __builtin_amdgcn_s_setprio(1);                                            \
    _Pragma("unroll")                                                         \
    for (int mf = 0; mf < 4; mf++)                                            \
      _Pragma("unroll")                                                       \
      for (int nf = 0; nf < 4; nf++)                                          \
        acc[mf + 4][nf] = __builtin_amdgcn_mfma_f32_16x16x32_bf16(            \
            avH[mf], bvv[nf], acc[mf + 4][nf], 0, 0, 0);                      \
    __builtin_amdgcn_s_setprio(0);                                            \
    __builtin_amdgcn_s_barrier();                                             \
  } while (0)

  for (int t = 0; t < nt; t += 2) {
    TILE(t,     avL0, bv0, avL1, bv1);
    TILE(t + 1, avL1, bv1, avL0, bv0);
  }
#undef TILE
#undef STAGE_A
#undef STAGE_B

  // epilogue: C/D frag map col=l&15, row=(l>>4)*4+r
  const int lr = (l >> 4) * 4;
#pragma unroll
  for (int mf = 0; mf < 8; mf++) {
    const int row0 = m0 + wm + mf * 16 + lr;
#pragma unroll
    for (int nf = 0; nf < 4; nf++) {
      const int col = n0 + wn + nf * 16 + fr;
      const float bcol = bias ? bias[col] : 0.f;
#pragma unroll
      for (int r = 0; r < 4; r++) {
        float v = acc[mf][nf][r];
        if constexpr (EPI == 2) {
          v += bcol;
          v = v >= 0.f ? v : SLOPE * v;
          ((ushort_t*)Cv)[(long)(row0 + r) * N + col] = f2bf(v);
        } else {
          ((ushort_t*)Cv)[(long)(row0 + r) * N + col] = f2bf(v);
        }
      }
    }
  }
}

// ---------------------------------------------------------------------------
// m97-style 128x128 NT GEMM (4 waves, BK=32), XCD-swizzled grid.
// EPI: 0 = bf16 | 2 = bias+lrelu->bf16 | 3 = +resid->f32 | 4 = bias+lrelu+resid->f32
// ---------------------------------------------------------------------------
template<int EPI, bool CAUSAL, bool KLIM>
__global__ __launch_bounds__(256)
void gemm_nt(const ushort_t* __restrict__ A, const ushort_t* __restrict__ B,
             void* __restrict__ Cv, const float* __restrict__ bias,
             const float* __restrict__ resid,
             int M, int N, int K, long sAb, long sBb, long sCb)
{
  __shared__ ushort_t lA[128 * 32];
  __shared__ ushort_t lB[128 * 32];
  const int tid = threadIdx.x;
  const int w = tid >> 6;
  const int l = tid & 63;
  // T1: bijective XCD swizzle (m204)
  const int nwg = gridDim.x * gridDim.y;
  const int orig = blockIdx.y * gridDim.x + blockIdx.x;
  const int q8 = nwg >> 3, r8 = nwg & 7;
  const int xcd = orig & 7, io = orig >> 3;
  const int logical = (xcd < r8 ? xcd * (q8 + 1) : r8 * (q8 + 1) + (xcd - r8) * q8) + io;
  const int m0 = (logical / gridDim.x) * 128;
  const int n0 = (logical % gridDim.x) * 128;
  if (CAUSAL && n0 > m0 + 127) return;
  const long bz = blockIdx.z;
  A += bz * sAb;
  B += bz * sBb;
  int Keff = K;
  if (KLIM) Keff = min(K, m0 + 128);

  const ushort_t* gA = A + (long)(m0 + w * 32 + (l >> 2)) * K + (l & 3) * 8;
  const ushort_t* gB = B + (long)(n0 + w * 32 + (l >> 2)) * K + (l & 3) * 8;
  ushort_t* lAw0 = &lA[(w * 32) * 32];
  ushort_t* lAw1 = &lA[(w * 32 + 16) * 32];
  ushort_t* lBw0 = &lB[(w * 32) * 32];
  ushort_t* lBw1 = &lB[(w * 32 + 16) * 32];
  const int wm = (w >> 1) * 64, wn = (w & 1) * 64;

  f32x4 acc[4][4] = {};

  for (int k0 = 0; k0 < Keff; k0 += 32) {
    gload_lds16(gA,                 lAw0);
    gload_lds16(gA + (long)16 * K,  lAw1);
    gload_lds16(gB,                 lBw0);
    gload_lds16(gB + (long)16 * K,  lBw1);
    gA += 32; gB += 32;
    __syncthreads();

    bf16v8 af[4], bfr[4];
#pragma unroll
    for (int m = 0; m < 4; m++)
      af[m] = *(const bf16v8*)&lA[(wm + m * 16 + (l & 15)) * 32 + (l >> 4) * 8];
#pragma unroll
    for (int n = 0; n < 4; n++)
      bfr[n] = *(const bf16v8*)&lB[(wn + n * 16 + (l & 15)) * 32 + (l >> 4) * 8];
#pragma unroll
    for (int m = 0; m < 4; m++)
#pragma unroll
      for (int n = 0; n < 4; n++)
        acc[m][n] = __builtin_amdgcn_mfma_f32_16x16x32_bf16(af[m], bfr[n], acc[m][n], 0, 0, 0);
    __syncthreads();
  }

  const int lr = (l >> 4) * 4;
  const int lc = l & 15;
#pragma unroll
  for (int m = 0; m < 4; m++) {
    const int row0 = m0 + wm + m * 16 + lr;
#pragma unroll
    for (int n = 0; n < 4; n++) {
      const int col = n0 + wn + n * 16 + lc;
#pragma unroll
      for (int r = 0; r < 4; r++) {
        float v = acc[m][n][r];
        const long idx = bz * sCb + (long)(row0 + r) * N + col;
        if constexpr (EPI == 0) {
          ((ushort_t*)Cv)[idx] = f2bf(v);
        } else if constexpr (EPI == 2) {
          v += bias[col];
          v = v >= 0.f ? v : SLOPE * v;
          ((ushort_t*)Cv)[idx] = f2bf(v);
        } else if constexpr (EPI == 3) {
          ((float*)Cv)[idx] = v + resid[idx];
        } else {
          v += bias[col];
          v = v >= 0.f ? v : SLOPE * v;
          ((float*)Cv)[idx] = v + resid[idx];
        }
      }
    }
  }
}

// ---------------------------------------------------------------------------
// LayerNorm: one 256-thread block per 1024-f32 row -> bf16 out
// ---------------------------------------------------------------------------
__global__ __launch_bounds__(256)
void ln_kernel(const float* __restrict__ x, const float* __restrict__ g,
               const float* __restrict__ bta, ushort_t* __restrict__ o)
{
  const long row = blockIdx.x;
  const int tid = threadIdx.x;
  const float4 v = *((const float4*)(x + row * 1024) + tid);
  float s  = v.x + v.y + v.z + v.w;
  float ss = v.x * v.x + v.y * v.y + v.z * v.z + v.w * v.w;
  for (int o2 = 32; o2 > 0; o2 >>= 1) {
    s  += __shfl_down(s, o2);
    ss += __shfl_down(ss, o2);
  }
  __shared__ float rs[4], rss[4];
  const int w = tid >> 6, l = tid & 63;
  if (l == 0) { rs[w] = s; rss[w] = ss; }
  __syncthreads();
  if (tid == 0) {
    float a = 0, c = 0;
    for (int i = 0; i < 4; i++) { a += rs[i]; c += rss[i]; }
    rs[0] = a; rss[0] = c;
  }
  __syncthreads();
  const float mean = rs[0] * (1.f / 1024.f);
  const float var  = rss[0] * (1.f / 1024.f) - mean * mean;
  const float rstd = rsqrtf(var + 1e-5f);
  const int c0 = tid * 4;
  ushort_t* orow = o + row * 1024;
  const float* vp = (const float*)&v;
#pragma unroll
  for (int i = 0; i < 4; i++)
    orow[c0 + i] = f2bf((vp[i] - mean) * rstd * g[c0 + i] + bta[c0 + i]);
}

// ---------------------------------------------------------------------------
// Causal softmax, IN PLACE on bf16 scores (scale 1/32), zero-fill t>s.
// ---------------------------------------------------------------------------
__global__ __launch_bounds__(256)
void softmax_kernel(ushort_t* __restrict__ sc)
{
  const long row = blockIdx.x;
  const int s = (int)(row & 2047);
  const int tid = threadIdx.x;
  ushort_t* srow = sc + row * 2048;
  const int t0 = tid * 8;
  u16x8 raw = *(const u16x8*)(srow + t0);
  float v[8];
  const float rsc = 1.0f / 32.0f;
  float mx = -3e38f;
#pragma unroll
  for (int i = 0; i < 8; i++) {
    float f = bf2f(raw[i]) * rsc;
    v[i] = (t0 + i <= s) ? f : -3e38f;
    mx = fmaxf(mx, v[i]);
  }
  for (int o = 32; o > 0; o >>= 1) mx = fmaxf(mx, __shfl_down(mx, o));
  __shared__ float red[8];
  const int w = tid >> 6, l = tid & 63;
  if (l == 0) red[w] = mx;
  __syncthreads();
  if (tid == 0) {
    float m2 = red[0];
    for (int i = 1; i < 4; i++) m2 = fmaxf(m2, red[i]);
    red[0] = m2;
  }
  __syncthreads();
  const float m = red[0];
  float sum = 0.f;
#pragma unroll
  for (int i = 0; i < 8; i++) {
    float e = (t0 + i <= s) ? __expf(v[i] - m) : 0.f;
    v[i] = e; sum += e;
  }
  for (int o = 32; o > 0; o >>= 1) sum += __shfl_down(sum, o);
  if (l == 0) red[4 + w] = sum;
  __syncthreads();
  if (tid == 0) {
    float s2 = 0;
    for (int i = 0; i < 4; i++) s2 += red[4 + i];
    red[0] = 1.0f / s2;
  }
  __syncthreads();
  const float inv = red[0];
#pragma unroll
  for (int i = 0; i < 8; i++) srow[t0 + i] = f2bf(v[i] * inv);
}

// ---------------------------------------------------------------------------
// Fused cast of all three MLP weights (one launch).
// ---------------------------------------------------------------------------
__global__ __launch_bounds__(256)
void cast3_bf16(const float* __restrict__ a, const float* __restrict__ b,
                const float* __restrict__ c, ushort_t* __restrict__ oa,
                ushort_t* __restrict__ ob, ushort_t* __restrict__ oc)
{
  long i = ((long)blockIdx.x * 256 + threadIdx.x) * 4;
  const float* src; ushort_t* dst;
  if (i < 4194304L)        { src = a; dst = oa; }
  else if (i < 8388608L)   { src = b + (0 - 4194304L); dst = ob - 4194304L; }
  else                     { src = c + (0 - 8388608L); dst = oc - 8388608L; }
  float4 v = *(const float4*)(src + i);
  dst[i]     = f2bf(v.x);
  dst[i + 1] = f2bf(v.y);
  dst[i + 2] = f2bf(v.z);
  dst[i + 3] = f2bf(v.w);
}

// Transpose-cast f32[1024][1024] -> bf16[1024][1024]^T for qk (z=0), ov (z=1)
__global__ __launch_bounds__(256)
void transpose_cast2(const float* __restrict__ s0, ushort_t* __restrict__ d0,
                     const float* __restrict__ s1, ushort_t* __restrict__ d1)
{
  __shared__ ushort_t t[32][33];
  const float* in = blockIdx.z ? s1 : s0;
  ushort_t*    o  = blockIdx.z ? d1 : d0;
  const int tx = threadIdx.x & 31, ty = threadIdx.x >> 5;
  const int r0 = blockIdx.y * 32, c0 = blockIdx.x * 32;
#pragma unroll
  for (int i = 0; i < 4; i++)
    t[ty + i * 8][tx] = f2bf(in[(long)(r0 + ty + i * 8) * 1024 + c0 + tx]);
  __syncthreads();
#pragma unroll
  for (int i = 0; i < 4; i++)
    o[(long)(c0 + ty + i * 8) * 1024 + r0 + tx] = t[tx][ty + i * 8];
}

// Transpose bf16[R][C] -> bf16[C][R], batched over z (h -> hT)
__global__ __launch_bounds__(256)
void transpose_bf16(const ushort_t* __restrict__ in, ushort_t* __restrict__ o,
                    int R, int C)
{
  __shared__ ushort_t t[32][33];
  const long bz = blockIdx.z;
  in += bz * (long)R * C;
  o  += bz * (long)R * C;
  const int tx = threadIdx.x & 31, ty = threadIdx.x >> 5;
  const int r0 = blockIdx.y * 32, c0 = blockIdx.x * 32;
#pragma unroll
  for (int i = 0; i < 4; i++)
    t[ty + i * 8][tx] = in[(long)(r0 + ty + i * 8) * C + c0 + tx];
  __syncthreads();
#pragma unroll
  for (int i = 0; i < 4; i++)
    o[(long)(c0 + ty + i * 8) * R + r0 + tx] = t[tx][ty + i * 8];
}

// ---------------------------------------------------------------------------
extern "C" void kernel_launch(void* const* d_in, const int* in_sizes, int n_in,
                              void* d_out, int out_size, void* d_ws, size_t ws_size,
                              hipStream_t stream)
{
  const float* x      = (const float*)d_in[0];
  const float* qk     = (const float*)d_in[1];
  const float* ov     = (const float*)d_in[2];
  const float* ln1_g  = (const float*)d_in[3];
  const float* ln1_b  = (const float*)d_in[4];
  const float* ln2_g  = (const float*)d_in[5];
  const float* ln2_b  = (const float*)d_in[6];
  const float* W_up   = (const float*)d_in[7];
  const float* b_up   = (const float*)d_in[8];
  const float* W_h    = (const float*)d_in[9];
  const float* b_h    = (const float*)d_in[10];
  const float* W_down = (const float*)d_in[11];
  const float* b_down = (const float*)d_in[12];
  float* out = (float*)d_out;          // also holds x1 (residual stream)
  char* ws = (char*)d_ws;
  const long MB = 1024L * 1024L;

  // Arena (base peak 132 MB; +32 MB full-a2 path if ws allows):
  ushort_t* wqT    = (ushort_t*)(ws +   0 * MB);  // [1024,1024] bf16
  ushort_t* woT    = (ushort_t*)(ws +   2 * MB);  // [1024,1024] bf16
  ushort_t* h      = (ushort_t*)(ws +   4 * MB);  // [8192,1024] bf16
  ushort_t* hT     = (ushort_t*)(ws +  20 * MB);  // [4][1024][2048] bf16
  ushort_t* q      = (ushort_t*)(ws +  36 * MB);  // [8192,1024] bf16
  ushort_t* scores = (ushort_t*)(ws +  52 * MB);  // [4][2048][2048] bf16 (in-place probs)
  // Phase B overlays (attention buffers dead by then):
  ushort_t* h2     = h;                           // [8192,1024] bf16 @4
  ushort_t* attnh  = q;                           // [8192,1024] bf16 @36
  ushort_t* wu     = hT;                          // [4096,1024] bf16 @20 (8 MB)
  ushort_t* wd     = (ushort_t*)(ws +  28 * MB);  // [1024,4096] bf16 @28 (8 MB)
  ushort_t* wh     = q;                           // [4096,4096] bf16 @36 (32 MB: 36..68)
  ushort_t* a1c    = (ushort_t*)(ws +  68 * MB);  // [4096,4096] bf16 chunk (32 MB)
  ushort_t* a2     = (ushort_t*)(ws + 100 * MB);  // chunk (32 MB) or full (64 MB)

  const bool bigws = ws_size >= (size_t)(166 * MB);  // full-a2 down-proj path

  // ---- Phase A: attention ----
  transpose_cast2<<<dim3(32, 32, 2), 256, 0, stream>>>(qk, wqT, ov, woT);
  ln_kernel<<<8192, 256, 0, stream>>>(x, ln1_g, ln1_b, h);
  transpose_bf16<<<dim3(32, 64, 4), 256, 0, stream>>>(h, hT, 2048, 1024);

  // q = h @ qk
  gemm_nt<0, false, false><<<dim3(8, 64, 1), 256, 0, stream>>>(
      h, wqT, q, nullptr, nullptr, 8192, 1024, 1024, 0, 0, 0);
  // scores = q @ h^T  (causal tiles skipped; bf16 store)
  gemm_nt<0, true, false><<<dim3(16, 16, 4), 256, 0, stream>>>(
      q, h, scores, nullptr, nullptr, 2048, 2048, 1024,
      2048L * 1024, 2048L * 1024, 2048L * 2048);
  // probs = causal softmax(scores/32), in place
  softmax_kernel<<<8192, 256, 0, stream>>>(scores);
  // attnh = probs @ h   (B = hT; K clamped at diagonal)
  gemm_nt<0, false, true><<<dim3(8, 16, 4), 256, 0, stream>>>(
      scores, hT, attnh, nullptr, nullptr, 2048, 1024, 2048,
      2048L * 2048, 1024L * 2048, 2048L * 1024);
  // x1 = x + attnh @ ov   -> stored in d_out
  gemm_nt<3, false, false><<<dim3(8, 64, 1), 256, 0, stream>>>(
      attnh, woT, out, nullptr, x, 8192, 1024, 1024, 0, 0, 0);

  // ---- Phase B: MLP ----
  ln_kernel<<<8192, 256, 0, stream>>>(out, ln2_g, ln2_b, h2);
  cast3_bf16<<<24576, 256, 0, stream>>>(W_up, W_down, W_h, wu, wd, wh);

  if (bigws) {
    // up + W_h per 4096-row chunk (nt8), a2 full 64MB; one M=8192 down-proj.
    for (int c = 0; c < 2; c++) {
      const long r0 = (long)c * 4096;
      gemm_nt8<2><<<dim3(16, 16, 1), 512, 131072, stream>>>(
          h2 + r0 * 1024, wu, a1c, b_up, 4096, 4096, 1024);
      gemm_nt8<2><<<dim3(16, 16, 1), 512, 131072, stream>>>(
          a1c, wh, a2 + r0 * 4096, b_h, 4096, 4096, 4096);
    }
    gemm_nt<4, false, false><<<dim3(8, 64, 1), 256, 0, stream>>>(
        a2, wd, out, b_down, out, 8192, 1024, 4096, 0, 0, 0);
  } else {
    for (int c = 0; c < 2; c++) {
      const long r0 = (long)c * 4096;
      gemm_nt8<2><<<dim3(16, 16, 1), 512, 131072, stream>>>(
          h2 + r0 * 1024, wu, a1c, b_up, 4096, 4096, 1024);
      gemm_nt8<2><<<dim3(16, 16, 1), 512, 131072, stream>>>(
          a1c, wh, a2, b_h, 4096, 4096, 4096);
      gemm_nt<4, false, false><<<dim3(8, 32, 1), 256, 0, stream>>>(
          a2, wd, out + r0 * 1024, b_down, out + r0 * 1024, 4096, 1024, 4096, 0, 0, 0);
    }
  }
}

// Round 8
// 671.339 us; speedup vs baseline: 1.0293x; 1.0293x over previous
//
#include <hip/hip_runtime.h>
#include <stdint.h>

// ---------------------------------------------------------------------------
// TransformerBlock on MI355X (gfx950)
//   x1  = x + ((softmax_causal((ln1(x)@qk)@ln1(x)^T / 32))@ln1(x))@ov
//   out = x1 + lrelu(lrelu(lrelu(ln2(x1)@W_up^T+b_up)@W_h^T+b_h)@W_down^T+b_down)
// Big MLP GEMMs: 256x256-tile 8-wave QUAD-BUFFERED BK=32 pipeline (R6-proven:
// distance-3 stage, one vmcnt(8)+barrier per tile) + T1 XCD swizzle.
// Everything else: m97-style 128x128 2-phase GEMM + T1. x1 lives in d_out.
// ---------------------------------------------------------------------------

typedef __attribute__((ext_vector_type(4))) float  f32x4;
typedef __attribute__((ext_vector_type(8))) __bf16 bf16v8;
typedef __attribute__((ext_vector_type(8))) unsigned short u16x8;
typedef unsigned short ushort_t;   // bf16 bit storage
typedef unsigned int   u32;

#define SLOPE 0.01f

__device__ __forceinline__ ushort_t f2bf(float f) {
  u32 u = __builtin_bit_cast(u32, f);
  u32 r = (u + 0x7FFFu + ((u >> 16) & 1u)) >> 16;
  return (ushort_t)r;
}
__device__ __forceinline__ float bf2f(ushort_t b) {
  u32 u = ((u32)b) << 16;
  return __builtin_bit_cast(float, u);
}

__device__ __forceinline__ void gload_lds16(const void* g, void* l) {
  __builtin_amdgcn_global_load_lds(
      (const __attribute__((address_space(1))) u32*)g,
      (__attribute__((address_space(3))) u32*)l, 16, 0, 0);
}

// ===========================================================================
// 256x256 8-wave quad-buffered NT GEMM:  C[M,N] = A[M,K] * B[N,K]^T  (bf16)
// BK=32; LDS = 4 rotating bufs x {A,B} x [256][32] bf16 = 4x32KB = 128KB.
// Swizzle (T2, rule-21 both-sides): 16B slot ^= (row>>1)&3; linear LDS dest,
// inverse-swizzled GLOBAL source, swizzled ds_read.  Conflicts: 0 (R4-R7).
// Phase t: {12 ds_read buf[t&3] | STAGE(t+3) | setprio(1) 32 MFMA setprio(0)
//           | vmcnt(8) + s_barrier}.  3 tile-groups in flight (~900+ cy cover).
// Liveness: STAGE(t+3) overwrites buf[(t-1)&3]; its reads were consumed
// (lgkm dep before MFMA) before phase t-1's barrier; STAGE issues after it.
// Drain tail: vmcnt 8/4/0 at t = nt-4/nt-3/nt-2.
// T1: bijective XCD swizzle (m204).  M,N mult 256, K mult 32.
// Measured (R6): 126 us @ W_h 4096^3-class, MfmaUtil 49%, ~1100 TF.
// R5/R7 schedule variants both regressed -> this is the kept local optimum.
// ===========================================================================
template<int EPI>
__global__ __launch_bounds__(512, 1)
void gemm_nt8(const ushort_t* __restrict__ A, const ushort_t* __restrict__ B,
              void* __restrict__ Cv, const float* __restrict__ bias,
              int M, int N, int K)
{
  extern __shared__ char smem[];
  const ushort_t* lds = (const ushort_t*)smem;
  const int tid = threadIdx.x;
  const int l   = tid & 63;
  // T1: bijective XCD swizzle (m204)
  const int nwg = gridDim.x * gridDim.y;
  const int orig = blockIdx.y * gridDim.x + blockIdx.x;
  const int q8 = nwg >> 3, r8 = nwg & 7;
  const int xcd = orig & 7, io = orig >> 3;
  const int logical = (xcd < r8 ? xcd * (q8 + 1) : r8 * (q8 + 1) + (xcd - r8) * q8) + io;
  const int m0 = (logical / gridDim.x) * 256;
  const int n0 = (logical % gridDim.x) * 256;
  const int wid = tid >> 6;
  const int wm = (wid >> 2) * 128;   // 2 wave-rows
  const int wn = (wid & 3) * 64;     // 4 wave-cols
  const int nt = K >> 5;             // K-tiles of 32

  // staging: thread fills LDS bytes [tid*16, tid*16+16): row=tid>>2,
  // 16B slot = tid&3; global source slot pre-swizzled: slot ^ ((row>>1)&3)
  const int  sg      = (((tid & 3) ^ ((tid >> 3) & 3))) * 8;  // elems
  const long rowA0   = (long)(m0 +       (tid >> 2)) * K;
  const long rowA1   = (long)(m0 + 128 + (tid >> 2)) * K;
  const long rowB0   = (long)(n0 +       (tid >> 2)) * K;
  const long rowB1   = (long)(n0 + 128 + (tid >> 2)) * K;
  const int  wbase16 = (tid & ~63) * 16;                      // bytes

#define STAGE(TT) do {                                                        \
    const long _k  = (long)(TT) * 32;                                         \
    char* _ra = (char*)smem + ((TT) & 3) * 32768 + wbase16;                   \
    char* _rb = _ra + 16384;                                                  \
    gload_lds16(A + rowA0 + _k + sg, _ra);                                    \
    gload_lds16(A + rowA1 + _k + sg, _ra + 8192);                             \
    gload_lds16(B + rowB0 + _k + sg, _rb);                                    \
    gload_lds16(B + rowB1 + _k + sg, _rb + 8192);                             \
  } while (0)

  // fragment-read constants
  const int fr  = l & 15;
  const int fsl = (((l >> 4) ^ ((l >> 1) & 3))) * 8;  // swizzled 16B slot, elems

  f32x4 acc[8][4] = {};

  // prologue: stage tiles 0..2 (12 loads), wait for tile 0's group
  STAGE(0);
  if (nt > 1) STAGE(1);
  if (nt > 2) STAGE(2);
  if (nt > 2)      { asm volatile("s_waitcnt vmcnt(8)" ::: "memory"); }
  else if (nt > 1) { asm volatile("s_waitcnt vmcnt(4)" ::: "memory"); }
  else             { asm volatile("s_waitcnt vmcnt(0)" ::: "memory"); }
  __builtin_amdgcn_s_barrier();
  __builtin_amdgcn_sched_barrier(0);

  for (int t = 0; t < nt; ++t) {
    const int buf = t & 3;
    const ushort_t* rA = lds + buf * 16384 +        (wm + fr) * 32 + fsl;
    const ushort_t* rB = lds + buf * 16384 + 8192 + (wn + fr) * 32 + fsl;
    bf16v8 av[8], bv[4];
#pragma unroll
    for (int mf = 0; mf < 8; mf++) av[mf] = *(const bf16v8*)(rA + mf * 512);
#pragma unroll
    for (int nf = 0; nf < 4; nf++) bv[nf] = *(const bf16v8*)(rB + nf * 512);

    if (t + 3 < nt) STAGE(t + 3);

    __builtin_amdgcn_s_setprio(1);
#pragma unroll
    for (int mf = 0; mf < 8; mf++)
#pragma unroll
      for (int nf = 0; nf < 4; nf++)
        acc[mf][nf] = __builtin_amdgcn_mfma_f32_16x16x32_bf16(
            av[mf], bv[nf], acc[mf][nf], 0, 0, 0);
    __builtin_amdgcn_s_setprio(0);

    // counted drain: retire tile t+1's group before next phase reads it
    if (t <= nt - 4) {
      asm volatile("s_waitcnt vmcnt(8)" ::: "memory");
      __builtin_amdgcn_s_barrier();
      __builtin_amdgcn_sched_barrier(0);
    } else if (t == nt - 3) {
      asm volatile("s_waitcnt vmcnt(4)" ::: "memory");
      __builtin_amdgcn_s_barrier();
      __builtin_amdgcn_sched_barrier(0);
    } else if (t == nt - 2) {
      asm volatile("s_waitcnt vmcnt(0)" ::: "memory");
      __builtin_amdgcn_s_barrier();
      __builtin_amdgcn_sched_barrier(0);
    }
    // t == nt-1: no further LDS consumers; fall through to epilogue
  }
#undef STAGE

  // epilogue: C/D frag map col=l&15, row=(l>>4)*4+r
  const int lr = (l >> 4) * 4;
#pragma unroll
  for (int mf = 0; mf < 8; mf++) {
    const int row0 = m0 + wm + mf * 16 + lr;
#pragma unroll
    for (int nf = 0; nf < 4; nf++) {
      const int col = n0 + wn + nf * 16 + fr;
      const float bcol = bias ? bias[col] : 0.f;
#pragma unroll
      for (int r = 0; r < 4; r++) {
        float v = acc[mf][nf][r];
        if constexpr (EPI == 2) {
          v += bcol;
          v = v >= 0.f ? v : SLOPE * v;
          ((ushort_t*)Cv)[(long)(row0 + r) * N + col] = f2bf(v);
        } else {
          ((ushort_t*)Cv)[(long)(row0 + r) * N + col] = f2bf(v);
        }
      }
    }
  }
}

// ---------------------------------------------------------------------------
// m97-style 128x128 NT GEMM (4 waves, BK=32), XCD-swizzled grid.
// EPI: 0 = bf16 | 2 = bias+lrelu->bf16 | 3 = +resid->f32 | 4 = bias+lrelu+resid->f32
// ---------------------------------------------------------------------------
template<int EPI, bool CAUSAL, bool KLIM>
__global__ __launch_bounds__(256)
void gemm_nt(const ushort_t* __restrict__ A, const ushort_t* __restrict__ B,
             void* __restrict__ Cv, const float* __restrict__ bias,
             const float* __restrict__ resid,
             int M, int N, int K, long sAb, long sBb, long sCb)
{
  __shared__ ushort_t lA[128 * 32];
  __shared__ ushort_t lB[128 * 32];
  const int tid = threadIdx.x;
  const int w = tid >> 6;
  const int l = tid & 63;
  // T1: bijective XCD swizzle (m204)
  const int nwg = gridDim.x * gridDim.y;
  const int orig = blockIdx.y * gridDim.x + blockIdx.x;
  const int q8 = nwg >> 3, r8 = nwg & 7;
  const int xcd = orig & 7, io = orig >> 3;
  const int logical = (xcd < r8 ? xcd * (q8 + 1) : r8 * (q8 + 1) + (xcd - r8) * q8) + io;
  const int m0 = (logical / gridDim.x) * 128;
  const int n0 = (logical % gridDim.x) * 128;
  if (CAUSAL && n0 > m0 + 127) return;
  const long bz = blockIdx.z;
  A += bz * sAb;
  B += bz * sBb;
  int Keff = K;
  if (KLIM) Keff = min(K, m0 + 128);

  const ushort_t* gA = A + (long)(m0 + w * 32 + (l >> 2)) * K + (l & 3) * 8;
  const ushort_t* gB = B + (long)(n0 + w * 32 + (l >> 2)) * K + (l & 3) * 8;
  ushort_t* lAw0 = &lA[(w * 32) * 32];
  ushort_t* lAw1 = &lA[(w * 32 + 16) * 32];
  ushort_t* lBw0 = &lB[(w * 32) * 32];
  ushort_t* lBw1 = &lB[(w * 32 + 16) * 32];
  const int wm = (w >> 1) * 64, wn = (w & 1) * 64;

  f32x4 acc[4][4] = {};

  for (int k0 = 0; k0 < Keff; k0 += 32) {
    gload_lds16(gA,                 lAw0);
    gload_lds16(gA + (long)16 * K,  lAw1);
    gload_lds16(gB,                 lBw0);
    gload_lds16(gB + (long)16 * K,  lBw1);
    gA += 32; gB += 32;
    __syncthreads();

    bf16v8 af[4], bfr[4];
#pragma unroll
    for (int m = 0; m < 4; m++)
      af[m] = *(const bf16v8*)&lA[(wm + m * 16 + (l & 15)) * 32 + (l >> 4) * 8];
#pragma unroll
    for (int n = 0; n < 4; n++)
      bfr[n] = *(const bf16v8*)&lB[(wn + n * 16 + (l & 15)) * 32 + (l >> 4) * 8];
#pragma unroll
    for (int m = 0; m < 4; m++)
#pragma unroll
      for (int n = 0; n < 4; n++)
        acc[m][n] = __builtin_amdgcn_mfma_f32_16x16x32_bf16(af[m], bfr[n], acc[m][n], 0, 0, 0);
    __syncthreads();
  }

  const int lr = (l >> 4) * 4;
  const int lc = l & 15;
#pragma unroll
  for (int m = 0; m < 4; m++) {
    const int row0 = m0 + wm + m * 16 + lr;
#pragma unroll
    for (int n = 0; n < 4; n++) {
      const int col = n0 + wn + n * 16 + lc;
#pragma unroll
      for (int r = 0; r < 4; r++) {
        float v = acc[m][n][r];
        const long idx = bz * sCb + (long)(row0 + r) * N + col;
        if constexpr (EPI == 0) {
          ((ushort_t*)Cv)[idx] = f2bf(v);
        } else if constexpr (EPI == 2) {
          v += bias[col];
          v = v >= 0.f ? v : SLOPE * v;
          ((ushort_t*)Cv)[idx] = f2bf(v);
        } else if constexpr (EPI == 3) {
          ((float*)Cv)[idx] = v + resid[idx];
        } else {
          v += bias[col];
          v = v >= 0.f ? v : SLOPE * v;
          ((float*)Cv)[idx] = v + resid[idx];
        }
      }
    }
  }
}

// ---------------------------------------------------------------------------
// LayerNorm: one 256-thread block per 1024-f32 row -> bf16 out
// ---------------------------------------------------------------------------
__global__ __launch_bounds__(256)
void ln_kernel(const float* __restrict__ x, const float* __restrict__ g,
               const float* __restrict__ bta, ushort_t* __restrict__ o)
{
  const long row = blockIdx.x;
  const int tid = threadIdx.x;
  const float4 v = *((const float4*)(x + row * 1024) + tid);
  float s  = v.x + v.y + v.z + v.w;
  float ss = v.x * v.x + v.y * v.y + v.z * v.z + v.w * v.w;
  for (int o2 = 32; o2 > 0; o2 >>= 1) {
    s  += __shfl_down(s, o2);
    ss += __shfl_down(ss, o2);
  }
  __shared__ float rs[4], rss[4];
  const int w = tid >> 6, l = tid & 63;
  if (l == 0) { rs[w] = s; rss[w] = ss; }
  __syncthreads();
  if (tid == 0) {
    float a = 0, c = 0;
    for (int i = 0; i < 4; i++) { a += rs[i]; c += rss[i]; }
    rs[0] = a; rss[0] = c;
  }
  __syncthreads();
  const float mean = rs[0] * (1.f / 1024.f);
  const float var  = rss[0] * (1.f / 1024.f) - mean * mean;
  const float rstd = rsqrtf(var + 1e-5f);
  const int c0 = tid * 4;
  ushort_t* orow = o + row * 1024;
  const float* vp = (const float*)&v;
#pragma unroll
  for (int i = 0; i < 4; i++)
    orow[c0 + i] = f2bf((vp[i] - mean) * rstd * g[c0 + i] + bta[c0 + i]);
}

// ---------------------------------------------------------------------------
// Causal softmax, IN PLACE on bf16 scores (scale 1/32), zero-fill t>s.
// ---------------------------------------------------------------------------
__global__ __launch_bounds__(256)
void softmax_kernel(ushort_t* __restrict__ sc)
{
  const long row = blockIdx.x;
  const int s = (int)(row & 2047);
  const int tid = threadIdx.x;
  ushort_t* srow = sc + row * 2048;
  const int t0 = tid * 8;
  u16x8 raw = *(const u16x8*)(srow + t0);
  float v[8];
  const float rsc = 1.0f / 32.0f;
  float mx = -3e38f;
#pragma unroll
  for (int i = 0; i < 8; i++) {
    float f = bf2f(raw[i]) * rsc;
    v[i] = (t0 + i <= s) ? f : -3e38f;
    mx = fmaxf(mx, v[i]);
  }
  for (int o = 32; o > 0; o >>= 1) mx = fmaxf(mx, __shfl_down(mx, o));
  __shared__ float red[8];
  const int w = tid >> 6, l = tid & 63;
  if (l == 0) red[w] = mx;
  __syncthreads();
  if (tid == 0) {
    float m2 = red[0];
    for (int i = 1; i < 4; i++) m2 = fmaxf(m2, red[i]);
    red[0] = m2;
  }
  __syncthreads();
  const float m = red[0];
  float sum = 0.f;
#pragma unroll
  for (int i = 0; i < 8; i++) {
    float e = (t0 + i <= s) ? __expf(v[i] - m) : 0.f;
    v[i] = e; sum += e;
  }
  for (int o = 32; o > 0; o >>= 1) sum += __shfl_down(sum, o);
  if (l == 0) red[4 + w] = sum;
  __syncthreads();
  if (tid == 0) {
    float s2 = 0;
    for (int i = 0; i < 4; i++) s2 += red[4 + i];
    red[0] = 1.0f / s2;
  }
  __syncthreads();
  const float inv = red[0];
#pragma unroll
  for (int i = 0; i < 8; i++) srow[t0 + i] = f2bf(v[i] * inv);
}

// ---------------------------------------------------------------------------
// Fused cast of all three MLP weights (one launch).
// ---------------------------------------------------------------------------
__global__ __launch_bounds__(256)
void cast3_bf16(const float* __restrict__ a, const float* __restrict__ b,
                const float* __restrict__ c, ushort_t* __restrict__ oa,
                ushort_t* __restrict__ ob, ushort_t* __restrict__ oc)
{
  long i = ((long)blockIdx.x * 256 + threadIdx.x) * 4;
  const float* src; ushort_t* dst;
  if (i < 4194304L)        { src = a; dst = oa; }
  else if (i < 8388608L)   { src = b + (0 - 4194304L); dst = ob - 4194304L; }
  else                     { src = c + (0 - 8388608L); dst = oc - 8388608L; }
  float4 v = *(const float4*)(src + i);
  dst[i]     = f2bf(v.x);
  dst[i + 1] = f2bf(v.y);
  dst[i + 2] = f2bf(v.z);
  dst[i + 3] = f2bf(v.w);
}

// Transpose-cast f32[1024][1024] -> bf16[1024][1024]^T for qk (z=0), ov (z=1)
__global__ __launch_bounds__(256)
void transpose_cast2(const float* __restrict__ s0, ushort_t* __restrict__ d0,
                     const float* __restrict__ s1, ushort_t* __restrict__ d1)
{
  __shared__ ushort_t t[32][33];
  const float* in = blockIdx.z ? s1 : s0;
  ushort_t*    o  = blockIdx.z ? d1 : d0;
  const int tx = threadIdx.x & 31, ty = threadIdx.x >> 5;
  const int r0 = blockIdx.y * 32, c0 = blockIdx.x * 32;
#pragma unroll
  for (int i = 0; i < 4; i++)
    t[ty + i * 8][tx] = f2bf(in[(long)(r0 + ty + i * 8) * 1024 + c0 + tx]);
  __syncthreads();
#pragma unroll
  for (int i = 0; i < 4; i++)
    o[(long)(c0 + ty + i * 8) * 1024 + r0 + tx] = t[tx][ty + i * 8];
}

// Transpose bf16[R][C] -> bf16[C][R], batched over z (h -> hT)
__global__ __launch_bounds__(256)
void transpose_bf16(const ushort_t* __restrict__ in, ushort_t* __restrict__ o,
                    int R, int C)
{
  __shared__ ushort_t t[32][33];
  const long bz = blockIdx.z;
  in += bz * (long)R * C;
  o  += bz * (long)R * C;
  const int tx = threadIdx.x & 31, ty = threadIdx.x >> 5;
  const int r0 = blockIdx.y * 32, c0 = blockIdx.x * 32;
#pragma unroll
  for (int i = 0; i < 4; i++)
    t[ty + i * 8][tx] = in[(long)(r0 + ty + i * 8) * C + c0 + tx];
  __syncthreads();
#pragma unroll
  for (int i = 0; i < 4; i++)
    o[(long)(c0 + ty + i * 8) * R + r0 + tx] = t[tx][ty + i * 8];
}

// ---------------------------------------------------------------------------
extern "C" void kernel_launch(void* const* d_in, const int* in_sizes, int n_in,
                              void* d_out, int out_size, void* d_ws, size_t ws_size,
                              hipStream_t stream)
{
  const float* x      = (const float*)d_in[0];
  const float* qk     = (const float*)d_in[1];
  const float* ov     = (const float*)d_in[2];
  const float* ln1_g  = (const float*)d_in[3];
  const float* ln1_b  = (const float*)d_in[4];
  const float* ln2_g  = (const float*)d_in[5];
  const float* ln2_b  = (const float*)d_in[6];
  const float* W_up   = (const float*)d_in[7];
  const float* b_up   = (const float*)d_in[8];
  const float* W_h    = (const float*)d_in[9];
  const float* b_h    = (const float*)d_in[10];
  const float* W_down = (const float*)d_in[11];
  const float* b_down = (const float*)d_in[12];
  float* out = (float*)d_out;          // also holds x1 (residual stream)
  char* ws = (char*)d_ws;
  const long MB = 1024L * 1024L;

  // Arena (base peak 132 MB; +32 MB full-a2 path if ws allows):
  ushort_t* wqT    = (ushort_t*)(ws +   0 * MB);  // [1024,1024] bf16
  ushort_t* woT    = (ushort_t*)(ws +   2 * MB);  // [1024,1024] bf16
  ushort_t* h      = (ushort_t*)(ws +   4 * MB);  // [8192,1024] bf16
  ushort_t* hT     = (ushort_t*)(ws +  20 * MB);  // [4][1024][2048] bf16
  ushort_t* q      = (ushort_t*)(ws +  36 * MB);  // [8192,1024] bf16
  ushort_t* scores = (ushort_t*)(ws +  52 * MB);  // [4][2048][2048] bf16 (in-place probs)
  // Phase B overlays (attention buffers dead by then):
  ushort_t* h2     = h;                           // [8192,1024] bf16 @4
  ushort_t* attnh  = q;                           // [8192,1024] bf16 @36
  ushort_t* wu     = hT;                          // [4096,1024] bf16 @20 (8 MB)
  ushort_t* wd     = (ushort_t*)(ws +  28 * MB);  // [1024,4096] bf16 @28 (8 MB)
  ushort_t* wh     = q;                           // [4096,4096] bf16 @36 (32 MB: 36..68)
  ushort_t* a1c    = (ushort_t*)(ws +  68 * MB);  // [4096,4096] bf16 chunk (32 MB)
  ushort_t* a2     = (ushort_t*)(ws + 100 * MB);  // chunk (32 MB) or full (64 MB)

  const bool bigws = ws_size >= (size_t)(166 * MB);  // full-a2 down-proj path

  // ---- Phase A: attention ----
  transpose_cast2<<<dim3(32, 32, 2), 256, 0, stream>>>(qk, wqT, ov, woT);
  ln_kernel<<<8192, 256, 0, stream>>>(x, ln1_g, ln1_b, h);
  transpose_bf16<<<dim3(32, 64, 4), 256, 0, stream>>>(h, hT, 2048, 1024);

  // q = h @ qk
  gemm_nt<0, false, false><<<dim3(8, 64, 1), 256, 0, stream>>>(
      h, wqT, q, nullptr, nullptr, 8192, 1024, 1024, 0, 0, 0);
  // scores = q @ h^T  (causal tiles skipped; bf16 store)
  gemm_nt<0, true, false><<<dim3(16, 16, 4), 256, 0, stream>>>(
      q, h, scores, nullptr, nullptr, 2048, 2048, 1024,
      2048L * 1024, 2048L * 1024, 2048L * 2048);
  // probs = causal softmax(scores/32), in place
  softmax_kernel<<<8192, 256, 0, stream>>>(scores);
  // attnh = probs @ h   (B = hT; K clamped at diagonal)
  gemm_nt<0, false, true><<<dim3(8, 16, 4), 256, 0, stream>>>(
      scores, hT, attnh, nullptr, nullptr, 2048, 1024, 2048,
      2048L * 2048, 1024L * 2048, 2048L * 1024);
  // x1 = x + attnh @ ov   -> stored in d_out
  gemm_nt<3, false, false><<<dim3(8, 64, 1), 256, 0, stream>>>(
      attnh, woT, out, nullptr, x, 8192, 1024, 1024, 0, 0, 0);

  // ---- Phase B: MLP ----
  ln_kernel<<<8192, 256, 0, stream>>>(out, ln2_g, ln2_b, h2);
  cast3_bf16<<<24576, 256, 0, stream>>>(W_up, W_down, W_h, wu, wd, wh);

  if (bigws) {
    // up + W_h per 4096-row chunk (nt8), a2 full 64MB; one M=8192 down-proj.
    for (int c = 0; c < 2; c++) {
      const long r0 = (long)c * 4096;
      gemm_nt8<2><<<dim3(16, 16, 1), 512, 131072, stream>>>(
          h2 + r0 * 1024, wu, a1c, b_up, 4096, 4096, 1024);
      gemm_nt8<2><<<dim3(16, 16, 1), 512, 131072, stream>>>(
          a1c, wh, a2 + r0 * 4096, b_h, 4096, 4096, 4096);
    }
    gemm_nt<4, false, false><<<dim3(8, 64, 1), 256, 0, stream>>>(
        a2, wd, out, b_down, out, 8192, 1024, 4096, 0, 0, 0);
  } else {
    for (int c = 0; c < 2; c++) {
      const long r0 = (long)c * 4096;
      gemm_nt8<2><<<dim3(16, 16, 1), 512, 131072, stream>>>(
          h2 + r0 * 1024, wu, a1c, b_up, 4096, 4096, 1024);
      gemm_nt8<2><<<dim3(16, 16, 1), 512, 131072, stream>>>(
          a1c, wh, a2, b_h, 4096, 4096, 4096);
      gemm_nt<4, false, false><<<dim3(8, 32, 1), 256, 0, stream>>>(
          a2, wd, out + r0 * 1024, b_down, out + r0 * 1024, 4096, 1024, 4096, 0, 0, 0);
    }
  }
}